// Round 10
// baseline (4857.005 us; speedup 1.0000x reference)
//
#include <hip/hip_runtime.h>
#include <stdint.h>
#include <math.h>

#define NN 12288
#define DD 128
#define KTOP 31
#define TCAND 64         // candidate set >= top-64 by bf16 key (R0-R5-verified margin)
#define CCAP 128         // compaction capacity
#define RPB 16           // rows per block; grid = 768
#define WPB 8            // waves per block (512 threads)
#define ITERS 48         // column iterations: 12288 / (WPB*32)

typedef __attribute__((ext_vector_type(8))) short bf16x8;
typedef __attribute__((ext_vector_type(4))) float f32x4;

__device__ __forceinline__ unsigned short f2bf(float x) {  // RNE, no NaN in our data
  unsigned int u = __float_as_uint(x);
  u += 0x7fffu + ((u >> 16) & 1u);
  return (unsigned short)(u >> 16);
}

__device__ __forceinline__ unsigned umed3(unsigned a, unsigned b, unsigned c) {
  unsigned d;
  asm("v_med3_u32 %0, %1, %2, %3" : "=v"(d) : "v"(a), "v"(b), "v"(c));
  return d;
}

// opaque zero: runtime 0, but compiler cannot prove it -> blocks CSE across reps
__device__ __forceinline__ unsigned opaque_zero() {
  unsigned z;
  asm volatile("v_mov_b32 %0, 0" : "=v"(z));
  return z;
}

#define PINS8(Lx, P) { \
  const unsigned p_ = (P); \
  _Pragma("unroll") \
  for (int i_ = 0; i_ < 7; ++i_) \
    Lx[i_] = umed3(p_, Lx[i_], Lx[i_ + 1]); \
  Lx[7] = Lx[7] > p_ ? Lx[7] : p_; }

// ---------------- Kernel 0: transpose W1,W2 ----------------
__global__ __launch_bounds__(128)
void wtrans_kernel(const float* __restrict__ W1, const float* __restrict__ W2,
                   float* __restrict__ W1T, float* __restrict__ W2T) {
  const int r = blockIdx.x, c = threadIdx.x;
  W1T[(size_t)c * DD + r] = W1[(size_t)r * DD + c];
  W2T[(size_t)c * DD + r] = W2[(size_t)r * DD + c];
}

// ---------------- Kernel 1: MLP + L2 normalize — PROBE x4 (idempotent reps) ----------------
__global__ __launch_bounds__(256)
void mlp_norm_kernel(const float* __restrict__ feat,
                     const float* __restrict__ W1T, const float* __restrict__ b1,
                     const float* __restrict__ W2T, const float* __restrict__ b2,
                     double* __restrict__ hn64, unsigned short* __restrict__ hnb) {
  __shared__ double bufA[16][DD];
  __shared__ double bufB[16][DD];
  __shared__ double mnorm[16];
  const int t = threadIdx.x;
  const int c = t & 127;
  const int g = t >> 7;
  const int row0 = blockIdx.x * 16 + g * 8;

  for (int rep = 0; rep < 4; ++rep) {
    const unsigned z = opaque_zero();
    #pragma unroll
    for (int rr = 0; rr < 8; ++rr) {
      unsigned u = __float_as_uint(feat[(size_t)(row0 + rr) * DD + c]) ^ z;
      bufA[g * 8 + rr][c] = (double)__uint_as_float(u);
    }
    __syncthreads();

    {
      double acc[8] = {0,0,0,0,0,0,0,0};
      for (int k = 0; k < DD; k += 2) {
        double w0 = (double)W1T[(size_t)k * DD + c];
        double w1 = (double)W1T[(size_t)(k + 1) * DD + c];
        #pragma unroll
        for (int rr = 0; rr < 8; ++rr) {
          double2 a2 = *(const double2*)(&bufA[g * 8 + rr][k]);
          acc[rr] = fma(w0, a2.x, acc[rr]);
          acc[rr] = fma(w1, a2.y, acc[rr]);
        }
      }
      double bb = (double)b1[c];
      #pragma unroll
      for (int rr = 0; rr < 8; ++rr)
        bufB[g * 8 + rr][c] = fmax(acc[rr] + bb, 0.0);
    }
    __syncthreads();
    {
      double acc[8] = {0,0,0,0,0,0,0,0};
      for (int k = 0; k < DD; k += 2) {
        double w0 = (double)W2T[(size_t)k * DD + c];
        double w1 = (double)W2T[(size_t)(k + 1) * DD + c];
        #pragma unroll
        for (int rr = 0; rr < 8; ++rr) {
          double2 a2 = *(const double2*)(&bufB[g * 8 + rr][k]);
          acc[rr] = fma(w0, a2.x, acc[rr]);
          acc[rr] = fma(w1, a2.y, acc[rr]);
        }
      }
      double bb = (double)b2[c];
      #pragma unroll
      for (int rr = 0; rr < 8; ++rr)
        bufA[g * 8 + rr][c] = acc[rr] + bb;
    }
    __syncthreads();

    const int lane = t & 63;
    const int w = t >> 6;
    #pragma unroll
    for (int r2 = 0; r2 < 4; ++r2) {
      int rr = w * 4 + r2;
      double x0 = bufA[rr][lane];
      double x1 = bufA[rr][lane + 64];
      double s = x0 * x0 + x1 * x1;
      #pragma unroll
      for (int d = 1; d < 64; d <<= 1)
        s += __shfl_xor(s, d);
      if (lane == 0) mnorm[rr] = fmax(sqrt(s), 1e-12);
    }
    __syncthreads();
    #pragma unroll
    for (int rr = 0; rr < 8; ++rr) {
      double v = bufA[g * 8 + rr][c] / mnorm[g * 8 + rr];
      hn64[(size_t)(row0 + rr) * DD + c] = v;
      hnb[(size_t)(row0 + rr) * DD + c] = f2bf((float)v);
    }
    __syncthreads();   // bufA reuse barrier before next rep
  }
}

// ---------------- Kernel 2a-ablate: loop skeleton WITHOUT ladder — PROBE x6 (dummy out) ----------------
__global__ __launch_bounds__(512, 6)
void simladder_nol_kernel(const unsigned short* __restrict__ hnb,
                          unsigned* __restrict__ kdummy) {
  const int t = threadIdx.x, lane = t & 63, wv = t >> 6;
  const int m = lane & 15, quad = lane >> 4;
  const int row0 = blockIdx.x * RPB;

  for (int rep = 0; rep < 6; ++rep) {
    const unsigned z = opaque_zero();
    bf16x8 afrag[4];
    #pragma unroll
    for (int kc = 0; kc < 4; ++kc) {
      uint4 u = *(const uint4*)(hnb + (size_t)(row0 + m) * DD + kc * 32 + quad * 8);
      u.x ^= z; u.y ^= z; u.z ^= z; u.w ^= z;
      afrag[kc] = *(bf16x8*)&u;
    }
    unsigned LA[8] = {0,0,0,0,0,0,0,0};
    unsigned LB[8] = {0,0,0,0,0,0,0,0};

    for (int it = 0; it < ITERS; ++it) {
      const int cb = it * (WPB * 32) + wv * 32;
      f32x4 acc0 = {0.0f, 0.0f, 0.0f, 0.0f};
      f32x4 acc1 = {0.0f, 0.0f, 0.0f, 0.0f};
      #pragma unroll
      for (int kc = 0; kc < 4; ++kc) {
        bf16x8 b0 = *(const bf16x8*)(hnb + (size_t)(cb + m) * DD + kc * 32 + quad * 8);
        bf16x8 b1 = *(const bf16x8*)(hnb + (size_t)(cb + 16 + m) * DD + kc * 32 + quad * 8);
        acc0 = __builtin_amdgcn_mfma_f32_16x16x32_bf16(b0, afrag[kc], acc0, 0, 0, 0);
        acc1 = __builtin_amdgcn_mfma_f32_16x16x32_bf16(b1, afrag[kc], acc1, 0, 0, 0);
      }
      #pragma unroll
      for (int r = 0; r < 4; ++r) {
        unsigned bf0 = f2bf(acc0[r]);
        unsigned s0 = (bf0 & 0x8000u) ? 0u : bf0;
        unsigned p0 = (s0 << 16) | (unsigned)(cb + quad * 4 + r);
        unsigned bf1 = f2bf(acc1[r]);
        unsigned s1 = (bf1 & 0x8000u) ? 0u : bf1;
        unsigned p1 = (s1 << 16) | (unsigned)(cb + 16 + quad * 4 + r);
        asm volatile("" :: "v"(p0), "v"(p1));   // keep-alive, no ladder (rule #17)
      }
    }
    unsigned* dst = kdummy + (size_t)(row0 + m) * 512 + (wv * 4 + quad) * 16;
    *(uint4*)(dst)      = make_uint4(LA[0], LA[1], LA[2], LA[3]);
    *(uint4*)(dst + 4)  = make_uint4(LA[4], LA[5], LA[6], LA[7]);
    *(uint4*)(dst + 8)  = make_uint4(LB[0], LB[1], LB[2], LB[3]);
    *(uint4*)(dst + 12) = make_uint4(LB[4], LB[5], LB[6], LB[7]);
  }
}

// ---------------- Kernel 2a: sim MFMA loop + dual depth-8 ladders — PROBE x6 (idempotent) ----------------
__global__ __launch_bounds__(512, 6)
void simladder_kernel(const unsigned short* __restrict__ hnb,
                      unsigned* __restrict__ kbuf) {
  const int t = threadIdx.x, lane = t & 63, wv = t >> 6;
  const int m = lane & 15, quad = lane >> 4;
  const int row0 = blockIdx.x * RPB;

  for (int rep = 0; rep < 6; ++rep) {
    const unsigned z = opaque_zero();
    bf16x8 afrag[4];
    #pragma unroll
    for (int kc = 0; kc < 4; ++kc) {
      uint4 u = *(const uint4*)(hnb + (size_t)(row0 + m) * DD + kc * 32 + quad * 8);
      u.x ^= z; u.y ^= z; u.z ^= z; u.w ^= z;
      afrag[kc] = *(bf16x8*)&u;
    }
    unsigned LA[8] = {0,0,0,0,0,0,0,0};
    unsigned LB[8] = {0,0,0,0,0,0,0,0};

    for (int it = 0; it < ITERS; ++it) {
      const int cb = it * (WPB * 32) + wv * 32;
      f32x4 acc0 = {0.0f, 0.0f, 0.0f, 0.0f};
      f32x4 acc1 = {0.0f, 0.0f, 0.0f, 0.0f};
      #pragma unroll
      for (int kc = 0; kc < 4; ++kc) {
        bf16x8 b0 = *(const bf16x8*)(hnb + (size_t)(cb + m) * DD + kc * 32 + quad * 8);
        bf16x8 b1 = *(const bf16x8*)(hnb + (size_t)(cb + 16 + m) * DD + kc * 32 + quad * 8);
        acc0 = __builtin_amdgcn_mfma_f32_16x16x32_bf16(b0, afrag[kc], acc0, 0, 0, 0);
        acc1 = __builtin_amdgcn_mfma_f32_16x16x32_bf16(b1, afrag[kc], acc1, 0, 0, 0);
      }
      #pragma unroll
      for (int r = 0; r < 4; ++r) {
        {
          unsigned bf = f2bf(acc0[r]);
          unsigned s = (bf & 0x8000u) ? 0u : bf;
          unsigned p = (s << 16) | (unsigned)(cb + quad * 4 + r);
          PINS8(LA, p)
        }
        {
          unsigned bf = f2bf(acc1[r]);
          unsigned s = (bf & 0x8000u) ? 0u : bf;
          unsigned p = (s << 16) | (unsigned)(cb + 16 + quad * 4 + r);
          PINS8(LB, p)
        }
      }
    }

    unsigned* dst = kbuf + (size_t)(row0 + m) * 512 + (wv * 4 + quad) * 16;
    *(uint4*)(dst)      = make_uint4(LA[0], LA[1], LA[2], LA[3]);
    *(uint4*)(dst + 4)  = make_uint4(LA[4], LA[5], LA[6], LA[7]);
    *(uint4*)(dst + 8)  = make_uint4(LB[0], LB[1], LB[2], LB[3]);
    *(uint4*)(dst + 12) = make_uint4(LB[4], LB[5], LB[6], LB[7]);
  }
}

// ---------------- Kernel 2b: select + fp64 rescore + top-31 — PROBE x6 (idempotent) ----------------
__global__ __launch_bounds__(256)
void select_kernel(const unsigned* __restrict__ kbuf,
                   const double* __restrict__ hn64,
                   float* __restrict__ resval, int* __restrict__ rescol) {
  __shared__ unsigned scand[4][CCAP];
  __shared__ double cres[4][CCAP];
  const int t = threadIdx.x, lane = t & 63, wv = t >> 6;
  const int row = blockIdx.x * 4 + wv;

  for (int rep = 0; rep < 6; ++rep) {
    const unsigned z = opaque_zero();
    unsigned k8[8];
    {
      const unsigned* src = kbuf + (size_t)row * 512 + lane * 8;
      uint4 a = *(const uint4*)(src);
      uint4 b = *(const uint4*)(src + 4);
      k8[0] = a.x ^ z; k8[1] = a.y ^ z; k8[2] = a.z ^ z; k8[3] = a.w ^ z;
      k8[4] = b.x ^ z; k8[5] = b.y ^ z; k8[6] = b.z ^ z; k8[7] = b.w ^ z;
    }

    unsigned lo = 0, hi = 0xFFFFu;
    while (lo < hi) {
      unsigned mid = (lo + hi + 1) >> 1;
      int c = 0;
      #pragma unroll
      for (int i = 0; i < 8; ++i) c += (int)((k8[i] >> 16) >= mid);
      #pragma unroll
      for (int d = 1; d < 64; d <<= 1) c += __shfl_xor(c, d);
      if (c >= TCAND) lo = mid; else hi = mid - 1;
    }
    const unsigned thr = lo;

    int cl = 0;
    #pragma unroll
    for (int i = 0; i < 8; ++i) cl += (int)((k8[i] >> 16) >= thr);
    int pre = cl;
    #pragma unroll
    for (int d = 1; d < 64; d <<= 1) {
      int y = __shfl_up(pre, d);
      if (lane >= d) pre += y;
    }
    const int total = __shfl(pre, 63);
    const int nc = total < CCAP ? total : CCAP;
    int slot = pre - cl;
    #pragma unroll
    for (int i = 0; i < 8; ++i) {
      if ((k8[i] >> 16) >= thr) {
        if (slot < CCAP) scand[wv][slot] = k8[i];
        ++slot;
      }
    }
    // same-wave LDS producer->consumer

    const double* arow = hn64 + (size_t)row * DD;
    const int hl = lane >> 5;
    const int kl = (lane & 31) * 4;
    const double a0 = arow[kl], a1 = arow[kl + 1], a2 = arow[kl + 2], a3 = arow[kl + 3];
    const int ng = (nc + 1) >> 1;
    for (int g = 0; g < ng; ++g) {
      const int ci = 2 * g + hl;
      double partial = 0.0;
      if (ci < nc) {
        const int col = (int)(scand[wv][ci] & 0xFFFFu);
        const double* brow = hn64 + (size_t)col * DD + kl;
        double2 b01 = *(const double2*)(brow);
        double2 b23 = *(const double2*)(brow + 2);
        partial = fma(a0, b01.x, fma(a1, b01.y, fma(a2, b23.x, a3 * b23.y)));
      }
      #pragma unroll
      for (int d = 1; d < 32; d <<= 1)
        partial += __shfl_xor(partial, d);
      if ((lane & 31) == 0 && ci < nc) cres[wv][ci] = partial;
    }
    double rv0 = -1.0e300, rv1 = -1.0e300;
    int rc0 = 0x7fffffff, rc1 = 0x7fffffff;
    if (lane < nc)      { rv0 = cres[wv][lane];      rc0 = (int)(scand[wv][lane] & 0xFFFFu); }
    if (lane + 64 < nc) { rv1 = cres[wv][lane + 64]; rc1 = (int)(scand[wv][lane + 64] & 0xFFFFu); }

    for (int itk = 0; itk < KTOP; ++itk) {
      bool f = (rv0 > rv1) || (rv0 == rv1 && rc0 < rc1);
      double bv = f ? rv0 : rv1;
      int bc = f ? rc0 : rc1;
      #pragma unroll
      for (int d = 1; d < 64; d <<= 1) {
        double ov = __shfl_xor(bv, d);
        int    oc = __shfl_xor(bc, d);
        bool tk = (ov > bv) || (ov == bv && oc < bc);
        bv = tk ? ov : bv;
        bc = tk ? oc : bc;
      }
      if (lane == itk) {
        resval[(size_t)row * KTOP + itk] = (float)fmax(bv, 0.0);
        rescol[(size_t)row * KTOP + itk] = bc;
      }
      if (rv0 == bv && rc0 == bc) rv0 = -1.0e300;
      else if (rv1 == bv && rc1 == bc) rv1 = -1.0e300;
    }
  }
}

// ---------------- Kernel 3: emit all rows ----------------
__global__ __launch_bounds__(256)
void emit_kernel(const float* __restrict__ resval, const int* __restrict__ rescol,
                 float* __restrict__ out) {
  const int row = blockIdx.x, t = threadIdx.x;
  float v = 0.0f; int c = 0;
  if (t < KTOP) {
    v = resval[(size_t)row * KTOP + t];
    c = rescol[(size_t)row * KTOP + t];
  }
  f32x4* orow = (f32x4*)(out + (size_t)row * NN);
  const f32x4 z = {0.0f, 0.0f, 0.0f, 0.0f};
  #pragma unroll
  for (int i = 0; i < NN / 4 / 256; ++i)
    __builtin_nontemporal_store(z, &orow[i * 256 + t]);
  __syncthreads();
  if (t < KTOP) out[(size_t)row * NN + c] = v;
}

extern "C" void kernel_launch(void* const* d_in, const int* in_sizes, int n_in,
                              void* d_out, int out_size, void* d_ws, size_t ws_size,
                              hipStream_t stream) {
  const float* feat = (const float*)d_in[0];
  const float* W1 = (const float*)d_in[1];
  const float* b1 = (const float*)d_in[2];
  const float* W2 = (const float*)d_in[3];
  const float* b2 = (const float*)d_in[4];
  float* out = (float*)d_out;

  double* hn64 = (double*)d_ws;
  unsigned short* hnb = (unsigned short*)(hn64 + (size_t)NN * DD);
  float* resval = (float*)(hnb + (size_t)NN * DD);
  int* rescol = (int*)(resval + (size_t)NN * KTOP);
  float* W1T = (float*)(rescol + (size_t)NN * KTOP);
  float* W2T = W1T + DD * DD;

  // kbuf (25 MB) at d_out+512MB (consumed before emit); dummy at d_out+384MB
  unsigned* kbuf   = (unsigned*)((char*)d_out + ((size_t)512 << 20));
  unsigned* kdummy = (unsigned*)((char*)d_out + ((size_t)384 << 20));

  wtrans_kernel<<<DD, DD, 0, stream>>>(W1, W2, W1T, W2T);
  mlp_norm_kernel<<<NN / 16, 256, 0, stream>>>(feat, W1T, b1, W2T, b2, hn64, hnb);
  simladder_nol_kernel<<<NN / RPB, 512, 0, stream>>>(hnb, kdummy);
  simladder_kernel<<<NN / RPB, 512, 0, stream>>>(hnb, kbuf);
  select_kernel<<<NN / 4, 256, 0, stream>>>(kbuf, hn64, resval, rescol);
  emit_kernel<<<NN, 256, 0, stream>>>(resval, rescol, out);
}

// Round 11
// 927.746 us; speedup vs baseline: 5.2353x; 5.2353x over previous
//
#include <hip/hip_runtime.h>
#include <stdint.h>
#include <math.h>

#define NN 12288
#define DD 128
#define KTOP 31
#define TCAND 64         // candidate set >= top-64 by bf16 key (R0-R9-verified margin)
#define CCAP 128         // compaction capacity
#define RPB 48           // rows per block; grid = 256 = exactly 1 block per CU
#define WPB 8            // waves per block (512 threads)
#define NIT 48           // column iterations: 12288 / (WPB*32)
#define KROW 516         // keybuf row stride in u32 (512 keys + 4 pad -> bank spread)

typedef __attribute__((ext_vector_type(8))) short bf16x8;
typedef __attribute__((ext_vector_type(4))) float f32x4;

__device__ __forceinline__ unsigned short f2bf(float x) {  // RNE, no NaN in our data
  unsigned int u = __float_as_uint(x);
  u += 0x7fffu + ((u >> 16) & 1u);
  return (unsigned short)(u >> 16);
}

__device__ __forceinline__ unsigned umed3(unsigned a, unsigned b, unsigned c) {
  unsigned d;
  asm("v_med3_u32 %0, %1, %2, %3" : "=v"(d) : "v"(a), "v"(b), "v"(c));
  return d;
}

#define PINS8(Lx, P) { \
  const unsigned p_ = (P); \
  _Pragma("unroll") \
  for (int i_ = 0; i_ < 7; ++i_) \
    Lx[i_] = umed3(p_, Lx[i_], Lx[i_ + 1]); \
  Lx[7] = Lx[7] > p_ ? Lx[7] : p_; }

// ladder update for one acc half: keys for row-group's row, cols COLBASE+quad*4+r
#define LKEY(ACC, LX, COLBASE) { \
  _Pragma("unroll") \
  for (int r_ = 0; r_ < 4; ++r_) { \
    unsigned bf_ = f2bf((ACC)[r_]); \
    unsigned s_ = (bf_ & 0x8000u) ? 0u : bf_; \
    unsigned p_k = (s_ << 16) | (unsigned)((COLBASE) + quad * 4 + r_); \
    PINS8(LX, p_k) } }

// ---------------- Kernel 0: transpose W1,W2 ----------------
__global__ __launch_bounds__(128)
void wtrans_kernel(const float* __restrict__ W1, const float* __restrict__ W2,
                   float* __restrict__ W1T, float* __restrict__ W2T) {
  const int r = blockIdx.x, c = threadIdx.x;
  W1T[(size_t)c * DD + r] = W1[(size_t)r * DD + c];
  W2T[(size_t)c * DD + r] = W2[(size_t)r * DD + c];
}

// ---------------- Kernel 1: MLP + L2 normalize (256 thr / 16 rows per block) ----------------
__global__ __launch_bounds__(256)
void mlp_norm_kernel(const float* __restrict__ feat,
                     const float* __restrict__ W1T, const float* __restrict__ b1,
                     const float* __restrict__ W2T, const float* __restrict__ b2,
                     double* __restrict__ hn64, unsigned short* __restrict__ hnb) {
  __shared__ double bufA[16][DD];
  __shared__ double bufB[16][DD];
  __shared__ double mnorm[16];
  const int t = threadIdx.x;
  const int c = t & 127;
  const int g = t >> 7;
  const int row0 = blockIdx.x * 16 + g * 8;

  #pragma unroll
  for (int rr = 0; rr < 8; ++rr)
    bufA[g * 8 + rr][c] = (double)feat[(size_t)(row0 + rr) * DD + c];
  __syncthreads();

  {
    double acc[8] = {0,0,0,0,0,0,0,0};
    for (int k = 0; k < DD; k += 2) {
      double w0 = (double)W1T[(size_t)k * DD + c];
      double w1 = (double)W1T[(size_t)(k + 1) * DD + c];
      #pragma unroll
      for (int rr = 0; rr < 8; ++rr) {
        double2 a2 = *(const double2*)(&bufA[g * 8 + rr][k]);
        acc[rr] = fma(w0, a2.x, acc[rr]);
        acc[rr] = fma(w1, a2.y, acc[rr]);
      }
    }
    double bb = (double)b1[c];
    #pragma unroll
    for (int rr = 0; rr < 8; ++rr)
      bufB[g * 8 + rr][c] = fmax(acc[rr] + bb, 0.0);
  }
  __syncthreads();
  {
    double acc[8] = {0,0,0,0,0,0,0,0};
    for (int k = 0; k < DD; k += 2) {
      double w0 = (double)W2T[(size_t)k * DD + c];
      double w1 = (double)W2T[(size_t)(k + 1) * DD + c];
      #pragma unroll
      for (int rr = 0; rr < 8; ++rr) {
        double2 a2 = *(const double2*)(&bufB[g * 8 + rr][k]);
        acc[rr] = fma(w0, a2.x, acc[rr]);
        acc[rr] = fma(w1, a2.y, acc[rr]);
      }
    }
    double bb = (double)b2[c];
    #pragma unroll
    for (int rr = 0; rr < 8; ++rr)
      bufA[g * 8 + rr][c] = acc[rr] + bb;
  }
  __syncthreads();

  const int lane = t & 63;
  const int w = t >> 6;
  #pragma unroll
  for (int r2 = 0; r2 < 4; ++r2) {
    int rr = w * 4 + r2;
    double x0 = bufA[rr][lane];
    double x1 = bufA[rr][lane + 64];
    double s = x0 * x0 + x1 * x1;
    #pragma unroll
    for (int d = 1; d < 64; d <<= 1)
      s += __shfl_xor(s, d);
    if (lane == 0) mnorm[rr] = fmax(sqrt(s), 1e-12);
  }
  __syncthreads();
  #pragma unroll
  for (int rr = 0; rr < 8; ++rr) {
    double v = bufA[g * 8 + rr][c] / mnorm[g * 8 + rr];
    hn64[(size_t)(row0 + rr) * DD + c] = v;
    hnb[(size_t)(row0 + rr) * DD + c] = f2bf((float)v);
  }
}

// ---------------- Kernel 2 (FUSED, RPB=48): sim + select + fp64 rescore + emit ----------------
// R10 probes: loop == line-request-rate bound (265us == skeleton; ladder free).
// Lever: per-block B-traffic amortization. RPB 16->48 => grid 256 = 1 block/CU,
// loop traffic /3 (~90us predicted). 3 afrag row-groups, 6 acc chains: 24 MFMA
// per 8 loads. Keys in LDS (no kbuf round-trip); tail in-kernel; zeros
// NT-streamed in-loop (R4/R6-proven free); direct scatter. Selection margins
// identical to R9 (64 streams/row x depth-8, stream length 192).
__global__ __launch_bounds__(512, 2)
void fused_kernel(const unsigned short* __restrict__ hnb,
                  const double* __restrict__ hn64,
                  float* __restrict__ out) {
  __shared__ unsigned keybuf[RPB][KROW];   // 99.1 KB
  __shared__ unsigned scand[WPB][CCAP];    // 4 KB
  __shared__ double cres[WPB][CCAP];       // 8 KB
  __shared__ float outv[RPB][KTOP];        // 6 KB
  __shared__ int   outc[RPB][KTOP];        // 6 KB   (total ~123 KB -> 1 block/CU)
  const int t = threadIdx.x, lane = t & 63, wv = t >> 6;
  const int m = lane & 15, quad = lane >> 4;
  const int row0 = blockIdx.x * RPB;

  // 3 register-resident A-fragment sets: rows row0+m, +16+m, +32+m
  bf16x8 af0[4], af1[4], af2[4];
  #pragma unroll
  for (int kc = 0; kc < 4; ++kc) {
    af0[kc] = *(const bf16x8*)(hnb + (size_t)(row0 + m) * DD + kc * 32 + quad * 8);
    af1[kc] = *(const bf16x8*)(hnb + (size_t)(row0 + 16 + m) * DD + kc * 32 + quad * 8);
    af2[kc] = *(const bf16x8*)(hnb + (size_t)(row0 + 32 + m) * DD + kc * 32 + quad * 8);
  }

  unsigned LA0[8] = {0,0,0,0,0,0,0,0}, LB0[8] = {0,0,0,0,0,0,0,0};
  unsigned LA1[8] = {0,0,0,0,0,0,0,0}, LB1[8] = {0,0,0,0,0,0,0,0};
  unsigned LA2[8] = {0,0,0,0,0,0,0,0}, LB2[8] = {0,0,0,0,0,0,0,0};

  // block-private output zero region: rows row0..row0+47 (48*NN/4 f32x4 units)
  f32x4* outz = (f32x4*)(out + (size_t)row0 * NN);
  const f32x4 z = {0.0f, 0.0f, 0.0f, 0.0f};

  for (int it = 0; it < NIT; ++it) {
    const int cb = it * (WPB * 32) + wv * 32;
    bf16x8 b0[4], b1[4];
    #pragma unroll
    for (int kc = 0; kc < 4; ++kc) {
      b0[kc] = *(const bf16x8*)(hnb + (size_t)(cb + m) * DD + kc * 32 + quad * 8);
      b1[kc] = *(const bf16x8*)(hnb + (size_t)(cb + 16 + m) * DD + kc * 32 + quad * 8);
    }
    f32x4 a00 = {0,0,0,0}, a01 = {0,0,0,0};
    f32x4 a10 = {0,0,0,0}, a11 = {0,0,0,0};
    f32x4 a20 = {0,0,0,0}, a21 = {0,0,0,0};
    #pragma unroll
    for (int kc = 0; kc < 4; ++kc) {
      a00 = __builtin_amdgcn_mfma_f32_16x16x32_bf16(b0[kc], af0[kc], a00, 0, 0, 0);
      a01 = __builtin_amdgcn_mfma_f32_16x16x32_bf16(b1[kc], af0[kc], a01, 0, 0, 0);
      a10 = __builtin_amdgcn_mfma_f32_16x16x32_bf16(b0[kc], af1[kc], a10, 0, 0, 0);
      a11 = __builtin_amdgcn_mfma_f32_16x16x32_bf16(b1[kc], af1[kc], a11, 0, 0, 0);
      a20 = __builtin_amdgcn_mfma_f32_16x16x32_bf16(b0[kc], af2[kc], a20, 0, 0, 0);
      a21 = __builtin_amdgcn_mfma_f32_16x16x32_bf16(b1[kc], af2[kc], a21, 0, 0, 0);
    }
    // in-loop NT zeros: 48*NN f32 / 48 iters / 512 thr = 6 f32x4 per thread
    #pragma unroll
    for (int j = 0; j < 6; ++j)
      __builtin_nontemporal_store(z, &outz[it * 3072 + j * 512 + t]);
    // ladder updates (lane owns rows row0+m/+16+m/+32+m; 24 keys)
    LKEY(a00, LA0, cb)      LKEY(a01, LB0, cb + 16)
    LKEY(a10, LA1, cb)      LKEY(a11, LB1, cb + 16)
    LKEY(a20, LA2, cb)      LKEY(a21, LB2, cb + 16)
  }

  // dump ladders: row lr = g16*16+m, stream slot (wv*4+quad): keys [slot*16 .. +16)
  {
    const int sbase = (wv * 4 + quad) * 16;
    unsigned* d0 = &keybuf[m][sbase];
    *(uint4*)(d0)     = make_uint4(LA0[0], LA0[1], LA0[2], LA0[3]);
    *(uint4*)(d0 + 4) = make_uint4(LA0[4], LA0[5], LA0[6], LA0[7]);
    *(uint4*)(d0 + 8) = make_uint4(LB0[0], LB0[1], LB0[2], LB0[3]);
    *(uint4*)(d0 + 12)= make_uint4(LB0[4], LB0[5], LB0[6], LB0[7]);
    unsigned* d1 = &keybuf[16 + m][sbase];
    *(uint4*)(d1)     = make_uint4(LA1[0], LA1[1], LA1[2], LA1[3]);
    *(uint4*)(d1 + 4) = make_uint4(LA1[4], LA1[5], LA1[6], LA1[7]);
    *(uint4*)(d1 + 8) = make_uint4(LB1[0], LB1[1], LB1[2], LB1[3]);
    *(uint4*)(d1 + 12)= make_uint4(LB1[4], LB1[5], LB1[6], LB1[7]);
    unsigned* d2 = &keybuf[32 + m][sbase];
    *(uint4*)(d2)     = make_uint4(LA2[0], LA2[1], LA2[2], LA2[3]);
    *(uint4*)(d2 + 4) = make_uint4(LA2[4], LA2[5], LA2[6], LA2[7]);
    *(uint4*)(d2 + 8) = make_uint4(LB2[0], LB2[1], LB2[2], LB2[3]);
    *(uint4*)(d2 + 12)= make_uint4(LB2[4], LB2[5], LB2[6], LB2[7]);
  }
  __syncthreads();

  // tail: 6 rows per wave; threshold select + coalesced fp64 rescore + top-31
  for (int ii = 0; ii < 6; ++ii) {
    const int lr = wv * 6 + ii;
    const int grow = row0 + lr;
    unsigned k8[8];
    #pragma unroll
    for (int i = 0; i < 8; ++i)
      k8[i] = keybuf[lr][i * 64 + lane];   // conflict-free (lane stride 1)

    unsigned lo = 0, hi = 0xFFFFu;
    while (lo < hi) {
      unsigned mid = (lo + hi + 1) >> 1;
      int c = 0;
      #pragma unroll
      for (int i = 0; i < 8; ++i) c += (int)((k8[i] >> 16) >= mid);
      #pragma unroll
      for (int d = 1; d < 64; d <<= 1) c += __shfl_xor(c, d);
      if (c >= TCAND) lo = mid; else hi = mid - 1;
    }
    const unsigned thr = lo;

    int cl = 0;
    #pragma unroll
    for (int i = 0; i < 8; ++i) cl += (int)((k8[i] >> 16) >= thr);
    int pre = cl;
    #pragma unroll
    for (int d = 1; d < 64; d <<= 1) {
      int y = __shfl_up(pre, d);
      if (lane >= d) pre += y;
    }
    const int total = __shfl(pre, 63);
    const int nc = total < CCAP ? total : CCAP;
    int slot = pre - cl;
    #pragma unroll
    for (int i = 0; i < 8; ++i) {
      if ((k8[i] >> 16) >= thr) {
        if (slot < CCAP) scand[wv][slot] = k8[i];
        ++slot;
      }
    }
    // same-wave LDS producer->consumer: compiler inserts lgkmcnt

    const double* arow = hn64 + (size_t)grow * DD;
    const int hl = lane >> 5;
    const int kl = (lane & 31) * 4;
    const double a0 = arow[kl], a1 = arow[kl + 1], a2 = arow[kl + 2], a3 = arow[kl + 3];
    const int ng = (nc + 1) >> 1;
    for (int g = 0; g < ng; ++g) {
      const int ci = 2 * g + hl;
      double partial = 0.0;
      if (ci < nc) {
        const int col = (int)(scand[wv][ci] & 0xFFFFu);
        const double* brow = hn64 + (size_t)col * DD + kl;
        double2 b01 = *(const double2*)(brow);
        double2 b23 = *(const double2*)(brow + 2);
        partial = fma(a0, b01.x, fma(a1, b01.y, fma(a2, b23.x, a3 * b23.y)));
      }
      #pragma unroll
      for (int d = 1; d < 32; d <<= 1)
        partial += __shfl_xor(partial, d);
      if ((lane & 31) == 0 && ci < nc) cres[wv][ci] = partial;
    }
    double rv0 = -1.0e300, rv1 = -1.0e300;
    int rc0 = 0x7fffffff, rc1 = 0x7fffffff;
    if (lane < nc)      { rv0 = cres[wv][lane];      rc0 = (int)(scand[wv][lane] & 0xFFFFu); }
    if (lane + 64 < nc) { rv1 = cres[wv][lane + 64]; rc1 = (int)(scand[wv][lane + 64] & 0xFFFFu); }

    for (int itk = 0; itk < KTOP; ++itk) {
      bool f = (rv0 > rv1) || (rv0 == rv1 && rc0 < rc1);
      double bv = f ? rv0 : rv1;
      int bc = f ? rc0 : rc1;
      #pragma unroll
      for (int d = 1; d < 64; d <<= 1) {
        double ov = __shfl_xor(bv, d);
        int    oc = __shfl_xor(bc, d);
        bool tk = (ov > bv) || (ov == bv && oc < bc);
        bv = tk ? ov : bv;
        bc = tk ? oc : bc;
      }
      if (lane == itk) {
        outv[lr][itk] = (float)fmax(bv, 0.0);
        outc[lr][itk] = bc;
      }
      if (rv0 == bv && rc0 == bc) rv0 = -1.0e300;
      else if (rv1 == bv && rc1 == bc) rv1 = -1.0e300;
    }
  }

  // each wave drains its own stores (zeros + gathers), then block-wide barrier
  // => all zeros retired before anyone scatters
  asm volatile("s_waitcnt vmcnt(0)" ::: "memory");
  __syncthreads();
  #pragma unroll
  for (int ii = 0; ii < 6; ++ii) {
    const int lr = wv * 6 + ii;
    if (lane < KTOP)
      out[(size_t)(row0 + lr) * NN + outc[lr][lane]] = outv[lr][lane];
  }
}

extern "C" void kernel_launch(void* const* d_in, const int* in_sizes, int n_in,
                              void* d_out, int out_size, void* d_ws, size_t ws_size,
                              hipStream_t stream) {
  const float* feat = (const float*)d_in[0];
  const float* W1 = (const float*)d_in[1];
  const float* b1 = (const float*)d_in[2];
  const float* W2 = (const float*)d_in[3];
  const float* b2 = (const float*)d_in[4];
  float* out = (float*)d_out;

  // ws: hn64 (12.6 MB) | hnb (3.1 MB) | W1T,W2T (128 KB)
  double* hn64 = (double*)d_ws;
  unsigned short* hnb = (unsigned short*)(hn64 + (size_t)NN * DD);
  float* W1T = (float*)(hnb + (size_t)NN * DD);
  float* W2T = W1T + DD * DD;

  wtrans_kernel<<<DD, DD, 0, stream>>>(W1, W2, W1T, W2T);
  mlp_norm_kernel<<<NN / 16, 256, 0, stream>>>(feat, W1T, b1, W2T, b2, hn64, hnb);
  fused_kernel<<<NN / RPB, 512, 0, stream>>>(hnb, hn64, out);
}

// Round 12
// 910.338 us; speedup vs baseline: 5.3354x; 1.0191x over previous
//
#include <hip/hip_runtime.h>
#include <stdint.h>
#include <math.h>

#define NN 12288
#define DD 128
#define KTOP 31
#define TCAND 64         // candidate set >= top-64 by bf16 key (R0-R11-verified margin)
#define CCAP 128         // compaction capacity
#define RPB 48           // rows per loop-block; grid = 256 = 1 block/CU
#define WPL 16           // waves per loop block (1024 threads -> 4 waves/SIMD)
#define NIT 24           // column iterations: 12288 / (WPL*32)
#define KPROW 1024       // keys per row (128 streams x depth 8); 4 KB = row output prefix

typedef __attribute__((ext_vector_type(8))) short bf16x8;
typedef __attribute__((ext_vector_type(4))) float f32x4;

__device__ __forceinline__ unsigned short f2bf(float x) {  // RNE, no NaN in our data
  unsigned int u = __float_as_uint(x);
  u += 0x7fffu + ((u >> 16) & 1u);
  return (unsigned short)(u >> 16);
}

__device__ __forceinline__ unsigned umed3(unsigned a, unsigned b, unsigned c) {
  unsigned d;
  asm("v_med3_u32 %0, %1, %2, %3" : "=v"(d) : "v"(a), "v"(b), "v"(c));
  return d;
}

#define PINS8(Lx, P) { \
  const unsigned p_ = (P); \
  _Pragma("unroll") \
  for (int i_ = 0; i_ < 7; ++i_) \
    Lx[i_] = umed3(p_, Lx[i_], Lx[i_ + 1]); \
  Lx[7] = Lx[7] > p_ ? Lx[7] : p_; }

#define LKEY(ACC, LX, COLBASE) { \
  _Pragma("unroll") \
  for (int r_ = 0; r_ < 4; ++r_) { \
    unsigned bf_ = f2bf((ACC)[r_]); \
    unsigned s_ = (bf_ & 0x8000u) ? 0u : bf_; \
    unsigned p_k = (s_ << 16) | (unsigned)((COLBASE) + quad * 4 + r_); \
    PINS8(LX, p_k) } }

// ---------------- Kernel 0: transpose W1,W2 ----------------
__global__ __launch_bounds__(128)
void wtrans_kernel(const float* __restrict__ W1, const float* __restrict__ W2,
                   float* __restrict__ W1T, float* __restrict__ W2T) {
  const int r = blockIdx.x, c = threadIdx.x;
  W1T[(size_t)c * DD + r] = W1[(size_t)r * DD + c];
  W2T[(size_t)c * DD + r] = W2[(size_t)r * DD + c];
}

// ---------------- Kernel 1: MLP + L2 normalize ----------------
// R12: bufA stored f32 (exact input; float4 LDS reads = half the layer-1 LDS
// instrs, same serial k FMA order -> bit-identical). Separate bufC for layer-2
// output. LDS 40 KB (was 64).
__global__ __launch_bounds__(256)
void mlp_norm_kernel(const float* __restrict__ feat,
                     const float* __restrict__ W1T, const float* __restrict__ b1,
                     const float* __restrict__ W2T, const float* __restrict__ b2,
                     double* __restrict__ hn64, unsigned short* __restrict__ hnb) {
  __shared__ float  bufA[16][DD];    // 8 KB (f32 input, exact)
  __shared__ double bufB[16][DD];    // 16 KB
  __shared__ double bufC[16][DD];    // 16 KB
  __shared__ double mnorm[16];
  const int t = threadIdx.x;
  const int c = t & 127;
  const int g = t >> 7;
  const int row0 = blockIdx.x * 16 + g * 8;

  #pragma unroll
  for (int rr = 0; rr < 8; ++rr)
    bufA[g * 8 + rr][c] = feat[(size_t)(row0 + rr) * DD + c];
  __syncthreads();

  {
    double acc[8] = {0,0,0,0,0,0,0,0};
    for (int k = 0; k < DD; k += 4) {
      double w0 = (double)W1T[(size_t)k * DD + c];
      double w1 = (double)W1T[(size_t)(k + 1) * DD + c];
      double w2 = (double)W1T[(size_t)(k + 2) * DD + c];
      double w3 = (double)W1T[(size_t)(k + 3) * DD + c];
      #pragma unroll
      for (int rr = 0; rr < 8; ++rr) {
        f32x4 a4 = *(const f32x4*)(&bufA[g * 8 + rr][k]);
        acc[rr] = fma(w0, (double)a4.x, acc[rr]);
        acc[rr] = fma(w1, (double)a4.y, acc[rr]);
        acc[rr] = fma(w2, (double)a4.z, acc[rr]);
        acc[rr] = fma(w3, (double)a4.w, acc[rr]);
      }
    }
    double bb = (double)b1[c];
    #pragma unroll
    for (int rr = 0; rr < 8; ++rr)
      bufB[g * 8 + rr][c] = fmax(acc[rr] + bb, 0.0);
  }
  __syncthreads();
  {
    double acc[8] = {0,0,0,0,0,0,0,0};
    for (int k = 0; k < DD; k += 2) {
      double w0 = (double)W2T[(size_t)k * DD + c];
      double w1 = (double)W2T[(size_t)(k + 1) * DD + c];
      #pragma unroll
      for (int rr = 0; rr < 8; ++rr) {
        double2 a2 = *(const double2*)(&bufB[g * 8 + rr][k]);
        acc[rr] = fma(w0, a2.x, acc[rr]);
        acc[rr] = fma(w1, a2.y, acc[rr]);
      }
    }
    double bb = (double)b2[c];
    #pragma unroll
    for (int rr = 0; rr < 8; ++rr)
      bufC[g * 8 + rr][c] = acc[rr] + bb;
  }
  __syncthreads();

  const int lane = t & 63;
  const int w = t >> 6;
  #pragma unroll
  for (int r2 = 0; r2 < 4; ++r2) {
    int rr = w * 4 + r2;
    double x0 = bufC[rr][lane];
    double x1 = bufC[rr][lane + 64];
    double s = x0 * x0 + x1 * x1;
    #pragma unroll
    for (int d = 1; d < 64; d <<= 1)
      s += __shfl_xor(s, d);
    if (lane == 0) mnorm[rr] = fmax(sqrt(s), 1e-12);
  }
  __syncthreads();
  #pragma unroll
  for (int rr = 0; rr < 8; ++rr) {
    double v = bufC[g * 8 + rr][c] / mnorm[g * 8 + rr];
    hn64[(size_t)(row0 + rr) * DD + c] = v;
    hnb[(size_t)(row0 + rr) * DD + c] = f2bf((float)v);
  }
}

// ---------------- Kernel 2: sim MFMA loop + ladders + in-loop zeros; keys -> row prefix ----------------
// RPB=48 (traffic/3, R11-proven) at 16 waves/block (4 waves/SIMD — R11's fused
// ran 2/SIMD, latency-starved). Zero LDS. Keys (4 KB/row) are dumped into each
// row's OWN output prefix (cols 0-1023): no other block writes those bytes, so
// no race; select re-zeros them after reading. Per-wave vmcnt(0) + barrier
// orders this block's zeros before its key dump.
__global__ __launch_bounds__(1024)
void simloop_kernel(const unsigned short* __restrict__ hnb,
                    float* __restrict__ out) {
  const int t = threadIdx.x, lane = t & 63, wv = t >> 6;   // wv 0..15
  const int m = lane & 15, quad = lane >> 4;
  const int row0 = blockIdx.x * RPB;

  bf16x8 af0[4], af1[4], af2[4];
  #pragma unroll
  for (int kc = 0; kc < 4; ++kc) {
    af0[kc] = *(const bf16x8*)(hnb + (size_t)(row0 + m) * DD + kc * 32 + quad * 8);
    af1[kc] = *(const bf16x8*)(hnb + (size_t)(row0 + 16 + m) * DD + kc * 32 + quad * 8);
    af2[kc] = *(const bf16x8*)(hnb + (size_t)(row0 + 32 + m) * DD + kc * 32 + quad * 8);
  }

  unsigned LA0[8] = {0,0,0,0,0,0,0,0}, LB0[8] = {0,0,0,0,0,0,0,0};
  unsigned LA1[8] = {0,0,0,0,0,0,0,0}, LB1[8] = {0,0,0,0,0,0,0,0};
  unsigned LA2[8] = {0,0,0,0,0,0,0,0}, LB2[8] = {0,0,0,0,0,0,0,0};

  f32x4* outz = (f32x4*)(out + (size_t)row0 * NN);   // 48 rows = 147456 f32x4
  const f32x4 z = {0.0f, 0.0f, 0.0f, 0.0f};

  for (int it = 0; it < NIT; ++it) {
    const int cb = it * (WPL * 32) + wv * 32;
    f32x4 a00 = {0,0,0,0}, a01 = {0,0,0,0};
    f32x4 a10 = {0,0,0,0}, a11 = {0,0,0,0};
    f32x4 a20 = {0,0,0,0}, a21 = {0,0,0,0};
    #pragma unroll
    for (int kc = 0; kc < 4; ++kc) {    // per-kc B loads: caps VGPR for 16-wave block
      bf16x8 b0 = *(const bf16x8*)(hnb + (size_t)(cb + m) * DD + kc * 32 + quad * 8);
      bf16x8 b1 = *(const bf16x8*)(hnb + (size_t)(cb + 16 + m) * DD + kc * 32 + quad * 8);
      a00 = __builtin_amdgcn_mfma_f32_16x16x32_bf16(b0, af0[kc], a00, 0, 0, 0);
      a01 = __builtin_amdgcn_mfma_f32_16x16x32_bf16(b1, af0[kc], a01, 0, 0, 0);
      a10 = __builtin_amdgcn_mfma_f32_16x16x32_bf16(b0, af1[kc], a10, 0, 0, 0);
      a11 = __builtin_amdgcn_mfma_f32_16x16x32_bf16(b1, af1[kc], a11, 0, 0, 0);
      a20 = __builtin_amdgcn_mfma_f32_16x16x32_bf16(b0, af2[kc], a20, 0, 0, 0);
      a21 = __builtin_amdgcn_mfma_f32_16x16x32_bf16(b1, af2[kc], a21, 0, 0, 0);
    }
    // in-loop NT zeros: 48*NN f32 / 24 iters / 1024 thr = 6 f32x4 per thread
    #pragma unroll
    for (int j = 0; j < 6; ++j)
      __builtin_nontemporal_store(z, &outz[it * 6144 + j * 1024 + t]);
    LKEY(a00, LA0, cb)      LKEY(a01, LB0, cb + 16)
    LKEY(a10, LA1, cb)      LKEY(a11, LB1, cb + 16)
    LKEY(a20, LA2, cb)      LKEY(a21, LB2, cb + 16)
  }

  // all zeros of this block retired before key dump overwrites row prefixes
  asm volatile("s_waitcnt vmcnt(0)" ::: "memory");
  __syncthreads();

  const int sbase = (wv * 4 + quad) * 16;   // 64 slots x 16 u32 = 1024 keys/row
  {
    unsigned* d0 = (unsigned*)(out + (size_t)(row0 + m) * NN) + sbase;
    *(uint4*)(d0)     = make_uint4(LA0[0], LA0[1], LA0[2], LA0[3]);
    *(uint4*)(d0 + 4) = make_uint4(LA0[4], LA0[5], LA0[6], LA0[7]);
    *(uint4*)(d0 + 8) = make_uint4(LB0[0], LB0[1], LB0[2], LB0[3]);
    *(uint4*)(d0 + 12)= make_uint4(LB0[4], LB0[5], LB0[6], LB0[7]);
    unsigned* d1 = (unsigned*)(out + (size_t)(row0 + 16 + m) * NN) + sbase;
    *(uint4*)(d1)     = make_uint4(LA1[0], LA1[1], LA1[2], LA1[3]);
    *(uint4*)(d1 + 4) = make_uint4(LA1[4], LA1[5], LA1[6], LA1[7]);
    *(uint4*)(d1 + 8) = make_uint4(LB1[0], LB1[1], LB1[2], LB1[3]);
    *(uint4*)(d1 + 12)= make_uint4(LB1[4], LB1[5], LB1[6], LB1[7]);
    unsigned* d2 = (unsigned*)(out + (size_t)(row0 + 32 + m) * NN) + sbase;
    *(uint4*)(d2)     = make_uint4(LA2[0], LA2[1], LA2[2], LA2[3]);
    *(uint4*)(d2 + 4) = make_uint4(LA2[4], LA2[5], LA2[6], LA2[7]);
    *(uint4*)(d2 + 8) = make_uint4(LB2[0], LB2[1], LB2[2], LB2[3]);
    *(uint4*)(d2 + 12)= make_uint4(LB2[4], LB2[5], LB2[6], LB2[7]);
  }
}

// ---------------- Kernel 3: select + fp64 rescore + top-31 + prefix-zero + scatter ----------------
// High-occupancy tail (R10 ground truth: ~117us at this shape). 16 keys/lane.
// No stores in flight during the rescore gathers; the 4 KB key-prefix of each
// row is re-zeroed after extract, drained, then scattered.
__global__ __launch_bounds__(256)
void select_kernel(const double* __restrict__ hn64, float* __restrict__ out) {
  __shared__ unsigned scand[4][CCAP];
  __shared__ double cres[4][CCAP];
  const int t = threadIdx.x, lane = t & 63, wv = t >> 6;
  const int row = blockIdx.x * 4 + wv;
  float* orow = out + (size_t)row * NN;

  unsigned k16[16];
  {
    const unsigned* src = (const unsigned*)orow + lane * 16;
    #pragma unroll
    for (int q = 0; q < 4; ++q) {
      uint4 a = *(const uint4*)(src + q * 4);
      k16[q * 4 + 0] = a.x; k16[q * 4 + 1] = a.y;
      k16[q * 4 + 2] = a.z; k16[q * 4 + 3] = a.w;
    }
  }

  unsigned lo = 0, hi = 0xFFFFu;
  while (lo < hi) {
    unsigned mid = (lo + hi + 1) >> 1;
    int c = 0;
    #pragma unroll
    for (int i = 0; i < 16; ++i) c += (int)((k16[i] >> 16) >= mid);
    #pragma unroll
    for (int d = 1; d < 64; d <<= 1) c += __shfl_xor(c, d);
    if (c >= TCAND) lo = mid; else hi = mid - 1;
  }
  const unsigned thr = lo;

  int cl = 0;
  #pragma unroll
  for (int i = 0; i < 16; ++i) cl += (int)((k16[i] >> 16) >= thr);
  int pre = cl;
  #pragma unroll
  for (int d = 1; d < 64; d <<= 1) {
    int y = __shfl_up(pre, d);
    if (lane >= d) pre += y;
  }
  const int total = __shfl(pre, 63);
  const int nc = total < CCAP ? total : CCAP;
  int slot = pre - cl;
  #pragma unroll
  for (int i = 0; i < 16; ++i) {
    if ((k16[i] >> 16) >= thr) {
      if (slot < CCAP) scand[wv][slot] = k16[i];
      ++slot;
    }
  }
  // same-wave LDS producer->consumer: compiler inserts lgkmcnt

  const double* arow = hn64 + (size_t)row * DD;
  const int hl = lane >> 5;
  const int kl = (lane & 31) * 4;
  const double a0 = arow[kl], a1 = arow[kl + 1], a2 = arow[kl + 2], a3 = arow[kl + 3];
  const int ng = (nc + 1) >> 1;
  for (int g = 0; g < ng; ++g) {
    const int ci = 2 * g + hl;
    double partial = 0.0;
    if (ci < nc) {
      const int col = (int)(scand[wv][ci] & 0xFFFFu);
      const double* brow = hn64 + (size_t)col * DD + kl;
      double2 b01 = *(const double2*)(brow);
      double2 b23 = *(const double2*)(brow + 2);
      partial = fma(a0, b01.x, fma(a1, b01.y, fma(a2, b23.x, a3 * b23.y)));
    }
    #pragma unroll
    for (int d = 1; d < 32; d <<= 1)
      partial += __shfl_xor(partial, d);
    if ((lane & 31) == 0 && ci < nc) cres[wv][ci] = partial;
  }
  double rv0 = -1.0e300, rv1 = -1.0e300;
  int rc0 = 0x7fffffff, rc1 = 0x7fffffff;
  if (lane < nc)      { rv0 = cres[wv][lane];      rc0 = (int)(scand[wv][lane] & 0xFFFFu); }
  if (lane + 64 < nc) { rv1 = cres[wv][lane + 64]; rc1 = (int)(scand[wv][lane + 64] & 0xFFFFu); }

  float fkv = 0.0f; int fkc = 0;
  for (int itk = 0; itk < KTOP; ++itk) {
    bool f = (rv0 > rv1) || (rv0 == rv1 && rc0 < rc1);
    double bv = f ? rv0 : rv1;
    int bc = f ? rc0 : rc1;
    #pragma unroll
    for (int d = 1; d < 64; d <<= 1) {
      double ov = __shfl_xor(bv, d);
      int    oc = __shfl_xor(bc, d);
      bool tk = (ov > bv) || (ov == bv && oc < bc);
      bv = tk ? ov : bv;
      bc = tk ? oc : bc;
    }
    if (lane == itk) { fkv = (float)fmax(bv, 0.0); fkc = bc; }
    if (rv0 == bv && rc0 == bc) rv0 = -1.0e300;
    else if (rv1 == bv && rc1 == bc) rv1 = -1.0e300;
  }

  // re-zero this row's 4 KB key prefix (cols 0-1023), drain, scatter
  {
    f32x4* zp = (f32x4*)orow;
    const f32x4 z = {0.0f, 0.0f, 0.0f, 0.0f};
    #pragma unroll
    for (int j = 0; j < 4; ++j)
      __builtin_nontemporal_store(z, &zp[j * 64 + lane]);
  }
  asm volatile("s_waitcnt vmcnt(0)" ::: "memory");
  if (lane < KTOP) orow[fkc] = fkv;
}

extern "C" void kernel_launch(void* const* d_in, const int* in_sizes, int n_in,
                              void* d_out, int out_size, void* d_ws, size_t ws_size,
                              hipStream_t stream) {
  const float* feat = (const float*)d_in[0];
  const float* W1 = (const float*)d_in[1];
  const float* b1 = (const float*)d_in[2];
  const float* W2 = (const float*)d_in[3];
  const float* b2 = (const float*)d_in[4];
  float* out = (float*)d_out;

  // ws: hn64 (12.6 MB) | hnb (3.1 MB) | W1T,W2T (128 KB)
  double* hn64 = (double*)d_ws;
  unsigned short* hnb = (unsigned short*)(hn64 + (size_t)NN * DD);
  float* W1T = (float*)(hnb + (size_t)NN * DD);
  float* W2T = W1T + DD * DD;

  wtrans_kernel<<<DD, DD, 0, stream>>>(W1, W2, W1T, W2T);
  mlp_norm_kernel<<<NN / 16, 256, 0, stream>>>(feat, W1T, b1, W2T, b2, hn64, hnb);
  simloop_kernel<<<NN / RPB, 1024, 0, stream>>>(hnb, out);
  select_kernel<<<NN / 4, 256, 0, stream>>>(hn64, out);
}

// Round 13
// 887.096 us; speedup vs baseline: 5.4752x; 1.0262x over previous
//
#include <hip/hip_runtime.h>
#include <stdint.h>
#include <math.h>

#define NN 12288
#define DD 128
#define KTOP 31
#define TCAND 64         // candidate set >= top-64 by bf16 key (R0-R12-verified margin)
#define CCAP 128         // compaction capacity
#define RPB 48           // rows per loop-block; grid = 256 = 1 block/CU
#define WPL 16           // waves per loop block (1024 threads -> 4 waves/SIMD)
#define NIT 24           // column iterations: 12288 / (WPL*32)
#define KPROW 1024       // keys per row (128 streams x depth 8); 4 KB = row output prefix

typedef __attribute__((ext_vector_type(8))) short bf16x8;
typedef __attribute__((ext_vector_type(4))) float f32x4;

__device__ __forceinline__ unsigned short f2bf(float x) {  // RNE, no NaN in our data
  unsigned int u = __float_as_uint(x);
  u += 0x7fffu + ((u >> 16) & 1u);
  return (unsigned short)(u >> 16);
}

__device__ __forceinline__ unsigned umed3(unsigned a, unsigned b, unsigned c) {
  unsigned d;
  asm("v_med3_u32 %0, %1, %2, %3" : "=v"(d) : "v"(a), "v"(b), "v"(c));
  return d;
}

#define PINS8(Lx, P) { \
  const unsigned p_ = (P); \
  _Pragma("unroll") \
  for (int i_ = 0; i_ < 7; ++i_) \
    Lx[i_] = umed3(p_, Lx[i_], Lx[i_ + 1]); \
  Lx[7] = Lx[7] > p_ ? Lx[7] : p_; }

#define LKEY(ACC, LX, COLBASE) { \
  _Pragma("unroll") \
  for (int r_ = 0; r_ < 4; ++r_) { \
    unsigned bf_ = f2bf((ACC)[r_]); \
    unsigned s_ = (bf_ & 0x8000u) ? 0u : bf_; \
    unsigned p_k = (s_ << 16) | (unsigned)((COLBASE) + quad * 4 + r_); \
    PINS8(LX, p_k) } }

// ---------------- Kernel 0: transpose W1,W2 ----------------
__global__ __launch_bounds__(128)
void wtrans_kernel(const float* __restrict__ W1, const float* __restrict__ W2,
                   float* __restrict__ W1T, float* __restrict__ W2T) {
  const int r = blockIdx.x, c = threadIdx.x;
  W1T[(size_t)c * DD + r] = W1[(size_t)r * DD + c];
  W2T[(size_t)c * DD + r] = W2[(size_t)r * DD + c];
}

// ---------------- Kernel 1: MLP + L2 normalize (byte-identical to R12) ----------------
__global__ __launch_bounds__(256)
void mlp_norm_kernel(const float* __restrict__ feat,
                     const float* __restrict__ W1T, const float* __restrict__ b1,
                     const float* __restrict__ W2T, const float* __restrict__ b2,
                     double* __restrict__ hn64, unsigned short* __restrict__ hnb) {
  __shared__ float  bufA[16][DD];    // 8 KB (f32 input, exact)
  __shared__ double bufB[16][DD];    // 16 KB
  __shared__ double bufC[16][DD];    // 16 KB
  __shared__ double mnorm[16];
  const int t = threadIdx.x;
  const int c = t & 127;
  const int g = t >> 7;
  const int row0 = blockIdx.x * 16 + g * 8;

  #pragma unroll
  for (int rr = 0; rr < 8; ++rr)
    bufA[g * 8 + rr][c] = feat[(size_t)(row0 + rr) * DD + c];
  __syncthreads();

  {
    double acc[8] = {0,0,0,0,0,0,0,0};
    for (int k = 0; k < DD; k += 4) {
      double w0 = (double)W1T[(size_t)k * DD + c];
      double w1 = (double)W1T[(size_t)(k + 1) * DD + c];
      double w2 = (double)W1T[(size_t)(k + 2) * DD + c];
      double w3 = (double)W1T[(size_t)(k + 3) * DD + c];
      #pragma unroll
      for (int rr = 0; rr < 8; ++rr) {
        f32x4 a4 = *(const f32x4*)(&bufA[g * 8 + rr][k]);
        acc[rr] = fma(w0, (double)a4.x, acc[rr]);
        acc[rr] = fma(w1, (double)a4.y, acc[rr]);
        acc[rr] = fma(w2, (double)a4.z, acc[rr]);
        acc[rr] = fma(w3, (double)a4.w, acc[rr]);
      }
    }
    double bb = (double)b1[c];
    #pragma unroll
    for (int rr = 0; rr < 8; ++rr)
      bufB[g * 8 + rr][c] = fmax(acc[rr] + bb, 0.0);
  }
  __syncthreads();
  {
    double acc[8] = {0,0,0,0,0,0,0,0};
    for (int k = 0; k < DD; k += 2) {
      double w0 = (double)W2T[(size_t)k * DD + c];
      double w1 = (double)W2T[(size_t)(k + 1) * DD + c];
      #pragma unroll
      for (int rr = 0; rr < 8; ++rr) {
        double2 a2 = *(const double2*)(&bufB[g * 8 + rr][k]);
        acc[rr] = fma(w0, a2.x, acc[rr]);
        acc[rr] = fma(w1, a2.y, acc[rr]);
      }
    }
    double bb = (double)b2[c];
    #pragma unroll
    for (int rr = 0; rr < 8; ++rr)
      bufC[g * 8 + rr][c] = acc[rr] + bb;
  }
  __syncthreads();

  const int lane = t & 63;
  const int w = t >> 6;
  #pragma unroll
  for (int r2 = 0; r2 < 4; ++r2) {
    int rr = w * 4 + r2;
    double x0 = bufC[rr][lane];
    double x1 = bufC[rr][lane + 64];
    double s = x0 * x0 + x1 * x1;
    #pragma unroll
    for (int d = 1; d < 64; d <<= 1)
      s += __shfl_xor(s, d);
    if (lane == 0) mnorm[rr] = fmax(sqrt(s), 1e-12);
  }
  __syncthreads();
  #pragma unroll
  for (int rr = 0; rr < 8; ++rr) {
    double v = bufC[g * 8 + rr][c] / mnorm[g * 8 + rr];
    hn64[(size_t)(row0 + rr) * DD + c] = v;
    hnb[(size_t)(row0 + rr) * DD + c] = f2bf((float)v);
  }
}

// ---------------- Kernel 2: sim MFMA loop (byte-identical to R12) ----------------
__global__ __launch_bounds__(1024)
void simloop_kernel(const unsigned short* __restrict__ hnb,
                    float* __restrict__ out) {
  const int t = threadIdx.x, lane = t & 63, wv = t >> 6;   // wv 0..15
  const int m = lane & 15, quad = lane >> 4;
  const int row0 = blockIdx.x * RPB;

  bf16x8 af0[4], af1[4], af2[4];
  #pragma unroll
  for (int kc = 0; kc < 4; ++kc) {
    af0[kc] = *(const bf16x8*)(hnb + (size_t)(row0 + m) * DD + kc * 32 + quad * 8);
    af1[kc] = *(const bf16x8*)(hnb + (size_t)(row0 + 16 + m) * DD + kc * 32 + quad * 8);
    af2[kc] = *(const bf16x8*)(hnb + (size_t)(row0 + 32 + m) * DD + kc * 32 + quad * 8);
  }

  unsigned LA0[8] = {0,0,0,0,0,0,0,0}, LB0[8] = {0,0,0,0,0,0,0,0};
  unsigned LA1[8] = {0,0,0,0,0,0,0,0}, LB1[8] = {0,0,0,0,0,0,0,0};
  unsigned LA2[8] = {0,0,0,0,0,0,0,0}, LB2[8] = {0,0,0,0,0,0,0,0};

  f32x4* outz = (f32x4*)(out + (size_t)row0 * NN);   // 48 rows = 147456 f32x4
  const f32x4 z = {0.0f, 0.0f, 0.0f, 0.0f};

  for (int it = 0; it < NIT; ++it) {
    const int cb = it * (WPL * 32) + wv * 32;
    f32x4 a00 = {0,0,0,0}, a01 = {0,0,0,0};
    f32x4 a10 = {0,0,0,0}, a11 = {0,0,0,0};
    f32x4 a20 = {0,0,0,0}, a21 = {0,0,0,0};
    #pragma unroll
    for (int kc = 0; kc < 4; ++kc) {    // per-kc B loads: caps VGPR for 16-wave block
      bf16x8 b0 = *(const bf16x8*)(hnb + (size_t)(cb + m) * DD + kc * 32 + quad * 8);
      bf16x8 b1 = *(const bf16x8*)(hnb + (size_t)(cb + 16 + m) * DD + kc * 32 + quad * 8);
      a00 = __builtin_amdgcn_mfma_f32_16x16x32_bf16(b0, af0[kc], a00, 0, 0, 0);
      a01 = __builtin_amdgcn_mfma_f32_16x16x32_bf16(b1, af0[kc], a01, 0, 0, 0);
      a10 = __builtin_amdgcn_mfma_f32_16x16x32_bf16(b0, af1[kc], a10, 0, 0, 0);
      a11 = __builtin_amdgcn_mfma_f32_16x16x32_bf16(b1, af1[kc], a11, 0, 0, 0);
      a20 = __builtin_amdgcn_mfma_f32_16x16x32_bf16(b0, af2[kc], a20, 0, 0, 0);
      a21 = __builtin_amdgcn_mfma_f32_16x16x32_bf16(b1, af2[kc], a21, 0, 0, 0);
    }
    // in-loop NT zeros: 48*NN f32 / 24 iters / 1024 thr = 6 f32x4 per thread
    #pragma unroll
    for (int j = 0; j < 6; ++j)
      __builtin_nontemporal_store(z, &outz[it * 6144 + j * 1024 + t]);
    LKEY(a00, LA0, cb)      LKEY(a01, LB0, cb + 16)
    LKEY(a10, LA1, cb)      LKEY(a11, LB1, cb + 16)
    LKEY(a20, LA2, cb)      LKEY(a21, LB2, cb + 16)
  }

  // all zeros of this block retired before key dump overwrites row prefixes
  asm volatile("s_waitcnt vmcnt(0)" ::: "memory");
  __syncthreads();

  const int sbase = (wv * 4 + quad) * 16;   // 64 slots x 16 u32 = 1024 keys/row
  {
    unsigned* d0 = (unsigned*)(out + (size_t)(row0 + m) * NN) + sbase;
    *(uint4*)(d0)     = make_uint4(LA0[0], LA0[1], LA0[2], LA0[3]);
    *(uint4*)(d0 + 4) = make_uint4(LA0[4], LA0[5], LA0[6], LA0[7]);
    *(uint4*)(d0 + 8) = make_uint4(LB0[0], LB0[1], LB0[2], LB0[3]);
    *(uint4*)(d0 + 12)= make_uint4(LB0[4], LB0[5], LB0[6], LB0[7]);
    unsigned* d1 = (unsigned*)(out + (size_t)(row0 + 16 + m) * NN) + sbase;
    *(uint4*)(d1)     = make_uint4(LA1[0], LA1[1], LA1[2], LA1[3]);
    *(uint4*)(d1 + 4) = make_uint4(LA1[4], LA1[5], LA1[6], LA1[7]);
    *(uint4*)(d1 + 8) = make_uint4(LB1[0], LB1[1], LB1[2], LB1[3]);
    *(uint4*)(d1 + 12)= make_uint4(LB1[4], LB1[5], LB1[6], LB1[7]);
    unsigned* d2 = (unsigned*)(out + (size_t)(row0 + 32 + m) * NN) + sbase;
    *(uint4*)(d2)     = make_uint4(LA2[0], LA2[1], LA2[2], LA2[3]);
    *(uint4*)(d2 + 4) = make_uint4(LA2[4], LA2[5], LA2[6], LA2[7]);
    *(uint4*)(d2 + 8) = make_uint4(LB2[0], LB2[1], LB2[2], LB2[3]);
    *(uint4*)(d2 + 12)= make_uint4(LB2[4], LB2[5], LB2[6], LB2[7]);
  }
}

// ---------------- Kernel 3: select + fp64 rescore + top-31 + prefix-zero + scatter ----------------
// R13: rescore gather widened to 4 candidates in flight. 16-lane group g4 owns
// candidate 4g+g4; each lane loads 8 consecutive doubles (64 B = one line; 16
// lanes cover the 1 KB row), 8 FMAs, 4-step in-group shfl_xor reduce. ng ~ nc/4
// iterations, 4 independent gathers in flight (R12 had 2, ~117 cyc/iter stall).
// fp64 reassociation only (tree shape change) — delta ~1e-16 vs ~1e-3 rank gaps.
__global__ __launch_bounds__(256)
void select_kernel(const double* __restrict__ hn64, float* __restrict__ out) {
  __shared__ unsigned scand[4][CCAP];
  __shared__ double cres[4][CCAP];
  const int t = threadIdx.x, lane = t & 63, wv = t >> 6;
  const int row = blockIdx.x * 4 + wv;
  float* orow = out + (size_t)row * NN;

  unsigned k16[16];
  {
    const unsigned* src = (const unsigned*)orow + lane * 16;
    #pragma unroll
    for (int q = 0; q < 4; ++q) {
      uint4 a = *(const uint4*)(src + q * 4);
      k16[q * 4 + 0] = a.x; k16[q * 4 + 1] = a.y;
      k16[q * 4 + 2] = a.z; k16[q * 4 + 3] = a.w;
    }
  }

  unsigned lo = 0, hi = 0xFFFFu;
  while (lo < hi) {
    unsigned mid = (lo + hi + 1) >> 1;
    int c = 0;
    #pragma unroll
    for (int i = 0; i < 16; ++i) c += (int)((k16[i] >> 16) >= mid);
    #pragma unroll
    for (int d = 1; d < 64; d <<= 1) c += __shfl_xor(c, d);
    if (c >= TCAND) lo = mid; else hi = mid - 1;
  }
  const unsigned thr = lo;

  int cl = 0;
  #pragma unroll
  for (int i = 0; i < 16; ++i) cl += (int)((k16[i] >> 16) >= thr);
  int pre = cl;
  #pragma unroll
  for (int d = 1; d < 64; d <<= 1) {
    int y = __shfl_up(pre, d);
    if (lane >= d) pre += y;
  }
  const int total = __shfl(pre, 63);
  const int nc = total < CCAP ? total : CCAP;
  int slot = pre - cl;
  #pragma unroll
  for (int i = 0; i < 16; ++i) {
    if ((k16[i] >> 16) >= thr) {
      if (slot < CCAP) scand[wv][slot] = k16[i];
      ++slot;
    }
  }
  // same-wave LDS producer->consumer: compiler inserts lgkmcnt

  // phase 3: 4-candidate-wide coalesced fp64 rescore
  const double* arow = hn64 + (size_t)row * DD;
  const int g4 = lane >> 4;          // candidate group (0..3): candidate 4g+g4
  const int kl = (lane & 15) * 8;    // this lane's 8-double chunk (64 B line)
  double a[8];
  #pragma unroll
  for (int i = 0; i < 8; ++i) a[i] = arow[kl + i];
  const int ng = (nc + 3) >> 2;
  for (int g = 0; g < ng; ++g) {
    const int ci = 4 * g + g4;
    double partial = 0.0;
    if (ci < nc) {
      const int col = (int)(scand[wv][ci] & 0xFFFFu);
      const double* brow = hn64 + (size_t)col * DD + kl;
      double2 b01 = *(const double2*)(brow);
      double2 b23 = *(const double2*)(brow + 2);
      double2 b45 = *(const double2*)(brow + 4);
      double2 b67 = *(const double2*)(brow + 6);
      partial = fma(a[0], b01.x, fma(a[1], b01.y, fma(a[2], b23.x, a[3] * b23.y)));
      partial = fma(a[4], b45.x, fma(a[5], b45.y, fma(a[6], b67.x, fma(a[7], b67.y, partial))));
    }
    #pragma unroll
    for (int d = 1; d < 16; d <<= 1)
      partial += __shfl_xor(partial, d);
    if ((lane & 15) == 0 && ci < nc) cres[wv][ci] = partial;
  }
  double rv0 = -1.0e300, rv1 = -1.0e300;
  int rc0 = 0x7fffffff, rc1 = 0x7fffffff;
  if (lane < nc)      { rv0 = cres[wv][lane];      rc0 = (int)(scand[wv][lane] & 0xFFFFu); }
  if (lane + 64 < nc) { rv1 = cres[wv][lane + 64]; rc1 = (int)(scand[wv][lane + 64] & 0xFFFFu); }

  float fkv = 0.0f; int fkc = 0;
  for (int itk = 0; itk < KTOP; ++itk) {
    bool f = (rv0 > rv1) || (rv0 == rv1 && rc0 < rc1);
    double bv = f ? rv0 : rv1;
    int bc = f ? rc0 : rc1;
    #pragma unroll
    for (int d = 1; d < 64; d <<= 1) {
      double ov = __shfl_xor(bv, d);
      int    oc = __shfl_xor(bc, d);
      bool tk = (ov > bv) || (ov == bv && oc < bc);
      bv = tk ? ov : bv;
      bc = tk ? oc : bc;
    }
    if (lane == itk) { fkv = (float)fmax(bv, 0.0); fkc = bc; }
    if (rv0 == bv && rc0 == bc) rv0 = -1.0e300;
    else if (rv1 == bv && rc1 == bc) rv1 = -1.0e300;
  }

  // re-zero this row's 4 KB key prefix (cols 0-1023), drain, scatter
  {
    f32x4* zp = (f32x4*)orow;
    const f32x4 z = {0.0f, 0.0f, 0.0f, 0.0f};
    #pragma unroll
    for (int j = 0; j < 4; ++j)
      __builtin_nontemporal_store(z, &zp[j * 64 + lane]);
  }
  asm volatile("s_waitcnt vmcnt(0)" ::: "memory");
  if (lane < KTOP) orow[fkc] = fkv;
}

extern "C" void kernel_launch(void* const* d_in, const int* in_sizes, int n_in,
                              void* d_out, int out_size, void* d_ws, size_t ws_size,
                              hipStream_t stream) {
  const float* feat = (const float*)d_in[0];
  const float* W1 = (const float*)d_in[1];
  const float* b1 = (const float*)d_in[2];
  const float* W2 = (const float*)d_in[3];
  const float* b2 = (const float*)d_in[4];
  float* out = (float*)d_out;

  // ws: hn64 (12.6 MB) | hnb (3.1 MB) | W1T,W2T (128 KB)
  double* hn64 = (double*)d_ws;
  unsigned short* hnb = (unsigned short*)(hn64 + (size_t)NN * DD);
  float* W1T = (float*)(hnb + (size_t)NN * DD);
  float* W2T = W1T + DD * DD;

  wtrans_kernel<<<DD, DD, 0, stream>>>(W1, W2, W1T, W2T);
  mlp_norm_kernel<<<NN / 16, 256, 0, stream>>>(feat, W1T, b1, W2T, b2, hn64, hnb);
  simloop_kernel<<<NN / RPB, 1024, 0, stream>>>(hnb, out);
  select_kernel<<<NN / 4, 256, 0, stream>>>(hn64, out);
}

// Round 14
// 881.682 us; speedup vs baseline: 5.5088x; 1.0061x over previous
//
#include <hip/hip_runtime.h>
#include <stdint.h>
#include <math.h>

#define NN 12288
#define DD 128
#define KTOP 31
#define TCAND 64         // candidate set >= top-64 by bf16 key (R0-R13-verified margin)
#define CCAP 128         // compaction capacity
#define RPB 48           // rows per loop-block; grid = 256 = 1 block/CU
#define WPL 16           // waves per loop block (1024 threads -> 4 waves/SIMD)
#define NIT 24           // column iterations: 12288 / (WPL*32)
#define KPROW 1024       // keys per row (128 streams x depth 8); 4 KB = row output prefix

typedef __attribute__((ext_vector_type(8))) short bf16x8;
typedef __attribute__((ext_vector_type(4))) float f32x4;

__device__ __forceinline__ unsigned short f2bf(float x) {  // RNE, no NaN in our data
  unsigned int u = __float_as_uint(x);
  u += 0x7fffu + ((u >> 16) & 1u);
  return (unsigned short)(u >> 16);
}

__device__ __forceinline__ unsigned umed3(unsigned a, unsigned b, unsigned c) {
  unsigned d;
  asm("v_med3_u32 %0, %1, %2, %3" : "=v"(d) : "v"(a), "v"(b), "v"(c));
  return d;
}

#define PINS8(Lx, P) { \
  const unsigned p_ = (P); \
  _Pragma("unroll") \
  for (int i_ = 0; i_ < 7; ++i_) \
    Lx[i_] = umed3(p_, Lx[i_], Lx[i_ + 1]); \
  Lx[7] = Lx[7] > p_ ? Lx[7] : p_; }

#define LKEY(ACC, LX, COLBASE) { \
  _Pragma("unroll") \
  for (int r_ = 0; r_ < 4; ++r_) { \
    unsigned bf_ = f2bf((ACC)[r_]); \
    unsigned s_ = (bf_ & 0x8000u) ? 0u : bf_; \
    unsigned p_k = (s_ << 16) | (unsigned)((COLBASE) + quad * 4 + r_); \
    PINS8(LX, p_k) } }

// ---------------- Kernel 0: transpose W1,W2 ----------------
__global__ __launch_bounds__(128)
void wtrans_kernel(const float* __restrict__ W1, const float* __restrict__ W2,
                   float* __restrict__ W1T, float* __restrict__ W2T) {
  const int r = blockIdx.x, c = threadIdx.x;
  W1T[(size_t)c * DD + r] = W1[(size_t)r * DD + c];
  W2T[(size_t)c * DD + r] = W2[(size_t)r * DD + c];
}

// ---------------- Kernel 1: MLP + L2 normalize (byte-identical to R12/R13) ----------------
__global__ __launch_bounds__(256)
void mlp_norm_kernel(const float* __restrict__ feat,
                     const float* __restrict__ W1T, const float* __restrict__ b1,
                     const float* __restrict__ W2T, const float* __restrict__ b2,
                     double* __restrict__ hn64, unsigned short* __restrict__ hnb) {
  __shared__ float  bufA[16][DD];    // 8 KB (f32 input, exact)
  __shared__ double bufB[16][DD];    // 16 KB
  __shared__ double bufC[16][DD];    // 16 KB
  __shared__ double mnorm[16];
  const int t = threadIdx.x;
  const int c = t & 127;
  const int g = t >> 7;
  const int row0 = blockIdx.x * 16 + g * 8;

  #pragma unroll
  for (int rr = 0; rr < 8; ++rr)
    bufA[g * 8 + rr][c] = feat[(size_t)(row0 + rr) * DD + c];
  __syncthreads();

  {
    double acc[8] = {0,0,0,0,0,0,0,0};
    for (int k = 0; k < DD; k += 4) {
      double w0 = (double)W1T[(size_t)k * DD + c];
      double w1 = (double)W1T[(size_t)(k + 1) * DD + c];
      double w2 = (double)W1T[(size_t)(k + 2) * DD + c];
      double w3 = (double)W1T[(size_t)(k + 3) * DD + c];
      #pragma unroll
      for (int rr = 0; rr < 8; ++rr) {
        f32x4 a4 = *(const f32x4*)(&bufA[g * 8 + rr][k]);
        acc[rr] = fma(w0, (double)a4.x, acc[rr]);
        acc[rr] = fma(w1, (double)a4.y, acc[rr]);
        acc[rr] = fma(w2, (double)a4.z, acc[rr]);
        acc[rr] = fma(w3, (double)a4.w, acc[rr]);
      }
    }
    double bb = (double)b1[c];
    #pragma unroll
    for (int rr = 0; rr < 8; ++rr)
      bufB[g * 8 + rr][c] = fmax(acc[rr] + bb, 0.0);
  }
  __syncthreads();
  {
    double acc[8] = {0,0,0,0,0,0,0,0};
    for (int k = 0; k < DD; k += 2) {
      double w0 = (double)W2T[(size_t)k * DD + c];
      double w1 = (double)W2T[(size_t)(k + 1) * DD + c];
      #pragma unroll
      for (int rr = 0; rr < 8; ++rr) {
        double2 a2 = *(const double2*)(&bufB[g * 8 + rr][k]);
        acc[rr] = fma(w0, a2.x, acc[rr]);
        acc[rr] = fma(w1, a2.y, acc[rr]);
      }
    }
    double bb = (double)b2[c];
    #pragma unroll
    for (int rr = 0; rr < 8; ++rr)
      bufC[g * 8 + rr][c] = acc[rr] + bb;
  }
  __syncthreads();

  const int lane = t & 63;
  const int w = t >> 6;
  #pragma unroll
  for (int r2 = 0; r2 < 4; ++r2) {
    int rr = w * 4 + r2;
    double x0 = bufC[rr][lane];
    double x1 = bufC[rr][lane + 64];
    double s = x0 * x0 + x1 * x1;
    #pragma unroll
    for (int d = 1; d < 64; d <<= 1)
      s += __shfl_xor(s, d);
    if (lane == 0) mnorm[rr] = fmax(sqrt(s), 1e-12);
  }
  __syncthreads();
  #pragma unroll
  for (int rr = 0; rr < 8; ++rr) {
    double v = bufC[g * 8 + rr][c] / mnorm[g * 8 + rr];
    hn64[(size_t)(row0 + rr) * DD + c] = v;
    hnb[(size_t)(row0 + rr) * DD + c] = f2bf((float)v);
  }
}

// ---------------- Kernel 2: sim MFMA loop + ladders; R14: per-block column-phase stagger ----------------
// All 32 blocks/XCD previously scanned columns in lockstep from col 0 while the
// NT store stream evicted hnb from L2 -> 200+ MB HBM re-fetch of a 3.1 MB array
// (R7/R11 counters). Stagger: same-XCD blocks (blockIdx>>3) start at 8 different
// phases -> misses spread, most blocks hit lines a sibling just pulled.
// Keys: same SET per ladder (rotation of the same 24 iterations); top-8 of a
// set is order-independent -> bit-identical output.
__global__ __launch_bounds__(1024)
void simloop_kernel(const unsigned short* __restrict__ hnb,
                    float* __restrict__ out) {
  const int t = threadIdx.x, lane = t & 63, wv = t >> 6;   // wv 0..15
  const int m = lane & 15, quad = lane >> 4;
  const int row0 = blockIdx.x * RPB;
  const int it0 = (int)(((blockIdx.x >> 3) * 3u) % NIT);   // same-XCD phase spread

  bf16x8 af0[4], af1[4], af2[4];
  #pragma unroll
  for (int kc = 0; kc < 4; ++kc) {
    af0[kc] = *(const bf16x8*)(hnb + (size_t)(row0 + m) * DD + kc * 32 + quad * 8);
    af1[kc] = *(const bf16x8*)(hnb + (size_t)(row0 + 16 + m) * DD + kc * 32 + quad * 8);
    af2[kc] = *(const bf16x8*)(hnb + (size_t)(row0 + 32 + m) * DD + kc * 32 + quad * 8);
  }

  unsigned LA0[8] = {0,0,0,0,0,0,0,0}, LB0[8] = {0,0,0,0,0,0,0,0};
  unsigned LA1[8] = {0,0,0,0,0,0,0,0}, LB1[8] = {0,0,0,0,0,0,0,0};
  unsigned LA2[8] = {0,0,0,0,0,0,0,0}, LB2[8] = {0,0,0,0,0,0,0,0};

  f32x4* outz = (f32x4*)(out + (size_t)row0 * NN);   // 48 rows = 147456 f32x4
  const f32x4 z = {0.0f, 0.0f, 0.0f, 0.0f};

  for (int itt = 0; itt < NIT; ++itt) {
    int it = itt + it0; if (it >= NIT) it -= NIT;    // staggered column phase
    const int cb = it * (WPL * 32) + wv * 32;
    f32x4 a00 = {0,0,0,0}, a01 = {0,0,0,0};
    f32x4 a10 = {0,0,0,0}, a11 = {0,0,0,0};
    f32x4 a20 = {0,0,0,0}, a21 = {0,0,0,0};
    #pragma unroll
    for (int kc = 0; kc < 4; ++kc) {    // per-kc B loads: caps VGPR for 16-wave block
      bf16x8 b0 = *(const bf16x8*)(hnb + (size_t)(cb + m) * DD + kc * 32 + quad * 8);
      bf16x8 b1 = *(const bf16x8*)(hnb + (size_t)(cb + 16 + m) * DD + kc * 32 + quad * 8);
      a00 = __builtin_amdgcn_mfma_f32_16x16x32_bf16(b0, af0[kc], a00, 0, 0, 0);
      a01 = __builtin_amdgcn_mfma_f32_16x16x32_bf16(b1, af0[kc], a01, 0, 0, 0);
      a10 = __builtin_amdgcn_mfma_f32_16x16x32_bf16(b0, af1[kc], a10, 0, 0, 0);
      a11 = __builtin_amdgcn_mfma_f32_16x16x32_bf16(b1, af1[kc], a11, 0, 0, 0);
      a20 = __builtin_amdgcn_mfma_f32_16x16x32_bf16(b0, af2[kc], a20, 0, 0, 0);
      a21 = __builtin_amdgcn_mfma_f32_16x16x32_bf16(b1, af2[kc], a21, 0, 0, 0);
    }
    // in-loop NT zeros: 48*NN f32 / 24 iters / 1024 thr = 6 f32x4 per thread
    #pragma unroll
    for (int j = 0; j < 6; ++j)
      __builtin_nontemporal_store(z, &outz[it * 6144 + j * 1024 + t]);
    LKEY(a00, LA0, cb)      LKEY(a01, LB0, cb + 16)
    LKEY(a10, LA1, cb)      LKEY(a11, LB1, cb + 16)
    LKEY(a20, LA2, cb)      LKEY(a21, LB2, cb + 16)
  }

  // all zeros of this block retired before key dump overwrites row prefixes
  asm volatile("s_waitcnt vmcnt(0)" ::: "memory");
  __syncthreads();

  const int sbase = (wv * 4 + quad) * 16;   // 64 slots x 16 u32 = 1024 keys/row
  {
    unsigned* d0 = (unsigned*)(out + (size_t)(row0 + m) * NN) + sbase;
    *(uint4*)(d0)     = make_uint4(LA0[0], LA0[1], LA0[2], LA0[3]);
    *(uint4*)(d0 + 4) = make_uint4(LA0[4], LA0[5], LA0[6], LA0[7]);
    *(uint4*)(d0 + 8) = make_uint4(LB0[0], LB0[1], LB0[2], LB0[3]);
    *(uint4*)(d0 + 12)= make_uint4(LB0[4], LB0[5], LB0[6], LB0[7]);
    unsigned* d1 = (unsigned*)(out + (size_t)(row0 + 16 + m) * NN) + sbase;
    *(uint4*)(d1)     = make_uint4(LA1[0], LA1[1], LA1[2], LA1[3]);
    *(uint4*)(d1 + 4) = make_uint4(LA1[4], LA1[5], LA1[6], LA1[7]);
    *(uint4*)(d1 + 8) = make_uint4(LB1[0], LB1[1], LB1[2], LB1[3]);
    *(uint4*)(d1 + 12)= make_uint4(LB1[4], LB1[5], LB1[6], LB1[7]);
    unsigned* d2 = (unsigned*)(out + (size_t)(row0 + 32 + m) * NN) + sbase;
    *(uint4*)(d2)     = make_uint4(LA2[0], LA2[1], LA2[2], LA2[3]);
    *(uint4*)(d2 + 4) = make_uint4(LA2[4], LA2[5], LA2[6], LA2[7]);
    *(uint4*)(d2 + 8) = make_uint4(LB2[0], LB2[1], LB2[2], LB2[3]);
    *(uint4*)(d2 + 12)= make_uint4(LB2[4], LB2[5], LB2[6], LB2[7]);
  }
}

// ---------------- Kernel 3: select + fp64 rescore + top-31 + prefix-zero + scatter ----------------
// R14: gather loop unrolled x2 -> 8 candidates in flight per wave (R13 had 4).
// Per-candidate dot math unchanged (same FMA chain); only more concurrency.
__global__ __launch_bounds__(256)
void select_kernel(const double* __restrict__ hn64, float* __restrict__ out) {
  __shared__ unsigned scand[4][CCAP];
  __shared__ double cres[4][CCAP];
  const int t = threadIdx.x, lane = t & 63, wv = t >> 6;
  const int row = blockIdx.x * 4 + wv;
  float* orow = out + (size_t)row * NN;

  unsigned k16[16];
  {
    const unsigned* src = (const unsigned*)orow + lane * 16;
    #pragma unroll
    for (int q = 0; q < 4; ++q) {
      uint4 a = *(const uint4*)(src + q * 4);
      k16[q * 4 + 0] = a.x; k16[q * 4 + 1] = a.y;
      k16[q * 4 + 2] = a.z; k16[q * 4 + 3] = a.w;
    }
  }

  unsigned lo = 0, hi = 0xFFFFu;
  while (lo < hi) {
    unsigned mid = (lo + hi + 1) >> 1;
    int c = 0;
    #pragma unroll
    for (int i = 0; i < 16; ++i) c += (int)((k16[i] >> 16) >= mid);
    #pragma unroll
    for (int d = 1; d < 64; d <<= 1) c += __shfl_xor(c, d);
    if (c >= TCAND) lo = mid; else hi = mid - 1;
  }
  const unsigned thr = lo;

  int cl = 0;
  #pragma unroll
  for (int i = 0; i < 16; ++i) cl += (int)((k16[i] >> 16) >= thr);
  int pre = cl;
  #pragma unroll
  for (int d = 1; d < 64; d <<= 1) {
    int y = __shfl_up(pre, d);
    if (lane >= d) pre += y;
  }
  const int total = __shfl(pre, 63);
  const int nc = total < CCAP ? total : CCAP;
  int slot = pre - cl;
  #pragma unroll
  for (int i = 0; i < 16; ++i) {
    if ((k16[i] >> 16) >= thr) {
      if (slot < CCAP) scand[wv][slot] = k16[i];
      ++slot;
    }
  }
  // same-wave LDS producer->consumer: compiler inserts lgkmcnt

  // phase 3: 8-candidate-in-flight coalesced fp64 rescore (2x unroll of R13)
  const double* arow = hn64 + (size_t)row * DD;
  const int g4 = lane >> 4;          // candidate group (0..3)
  const int kl = (lane & 15) * 8;    // this lane's 8-double chunk (64 B line)
  double a[8];
  #pragma unroll
  for (int i = 0; i < 8; ++i) a[i] = arow[kl + i];
  const int ng = (nc + 7) >> 3;      // 2 candidates per group per iteration
  for (int g = 0; g < ng; ++g) {
    const int ci0 = 8 * g + g4;
    const int ci1 = ci0 + 4;
    double p0 = 0.0, p1 = 0.0;
    if (ci0 < nc) {
      const int col = (int)(scand[wv][ci0] & 0xFFFFu);
      const double* brow = hn64 + (size_t)col * DD + kl;
      double2 b01 = *(const double2*)(brow);
      double2 b23 = *(const double2*)(brow + 2);
      double2 b45 = *(const double2*)(brow + 4);
      double2 b67 = *(const double2*)(brow + 6);
      p0 = fma(a[0], b01.x, fma(a[1], b01.y, fma(a[2], b23.x, a[3] * b23.y)));
      p0 = fma(a[4], b45.x, fma(a[5], b45.y, fma(a[6], b67.x, fma(a[7], b67.y, p0))));
    }
    if (ci1 < nc) {
      const int col = (int)(scand[wv][ci1] & 0xFFFFu);
      const double* brow = hn64 + (size_t)col * DD + kl;
      double2 b01 = *(const double2*)(brow);
      double2 b23 = *(const double2*)(brow + 2);
      double2 b45 = *(const double2*)(brow + 4);
      double2 b67 = *(const double2*)(brow + 6);
      p1 = fma(a[0], b01.x, fma(a[1], b01.y, fma(a[2], b23.x, a[3] * b23.y)));
      p1 = fma(a[4], b45.x, fma(a[5], b45.y, fma(a[6], b67.x, fma(a[7], b67.y, p1))));
    }
    #pragma unroll
    for (int d = 1; d < 16; d <<= 1) {
      p0 += __shfl_xor(p0, d);
      p1 += __shfl_xor(p1, d);
    }
    if ((lane & 15) == 0) {
      if (ci0 < nc) cres[wv][ci0] = p0;
      if (ci1 < nc) cres[wv][ci1] = p1;
    }
  }
  double rv0 = -1.0e300, rv1 = -1.0e300;
  int rc0 = 0x7fffffff, rc1 = 0x7fffffff;
  if (lane < nc)      { rv0 = cres[wv][lane];      rc0 = (int)(scand[wv][lane] & 0xFFFFu); }
  if (lane + 64 < nc) { rv1 = cres[wv][lane + 64]; rc1 = (int)(scand[wv][lane + 64] & 0xFFFFu); }

  float fkv = 0.0f; int fkc = 0;
  for (int itk = 0; itk < KTOP; ++itk) {
    bool f = (rv0 > rv1) || (rv0 == rv1 && rc0 < rc1);
    double bv = f ? rv0 : rv1;
    int bc = f ? rc0 : rc1;
    #pragma unroll
    for (int d = 1; d < 64; d <<= 1) {
      double ov = __shfl_xor(bv, d);
      int    oc = __shfl_xor(bc, d);
      bool tk = (ov > bv) || (ov == bv && oc < bc);
      bv = tk ? ov : bv;
      bc = tk ? oc : bc;
    }
    if (lane == itk) { fkv = (float)fmax(bv, 0.0); fkc = bc; }
    if (rv0 == bv && rc0 == bc) rv0 = -1.0e300;
    else if (rv1 == bv && rc1 == bc) rv1 = -1.0e300;
  }

  // re-zero this row's 4 KB key prefix (cols 0-1023), drain, scatter
  {
    f32x4* zp = (f32x4*)orow;
    const f32x4 z = {0.0f, 0.0f, 0.0f, 0.0f};
    #pragma unroll
    for (int j = 0; j < 4; ++j)
      __builtin_nontemporal_store(z, &zp[j * 64 + lane]);
  }
  asm volatile("s_waitcnt vmcnt(0)" ::: "memory");
  if (lane < KTOP) orow[fkc] = fkv;
}

extern "C" void kernel_launch(void* const* d_in, const int* in_sizes, int n_in,
                              void* d_out, int out_size, void* d_ws, size_t ws_size,
                              hipStream_t stream) {
  const float* feat = (const float*)d_in[0];
  const float* W1 = (const float*)d_in[1];
  const float* b1 = (const float*)d_in[2];
  const float* W2 = (const float*)d_in[3];
  const float* b2 = (const float*)d_in[4];
  float* out = (float*)d_out;

  // ws: hn64 (12.6 MB) | hnb (3.1 MB) | W1T,W2T (128 KB)
  double* hn64 = (double*)d_ws;
  unsigned short* hnb = (unsigned short*)(hn64 + (size_t)NN * DD);
  float* W1T = (float*)(hnb + (size_t)NN * DD);
  float* W2T = W1T + DD * DD;

  wtrans_kernel<<<DD, DD, 0, stream>>>(W1, W2, W1T, W2T);
  mlp_norm_kernel<<<NN / 16, 256, 0, stream>>>(feat, W1T, b1, W2T, b2, hn64, hnb);
  simloop_kernel<<<NN / RPB, 1024, 0, stream>>>(hnb, out);
  select_kernel<<<NN / 4, 256, 0, stream>>>(hn64, out);
}